// Round 4
// baseline (3295.113 us; speedup 1.0000x reference)
//
#include <hip/hip_runtime.h>
#include <hip/hip_fp16.h>
#include <hip/hip_cooperative_groups.h>

namespace cg = cooperative_groups;

#define STEP 0.01f
#define D 64
#define NUM_LAYERS 10
#define GRID 1024

union H8 { uint4 u; __half2 h2[4]; __half h[8]; };

// ---------------- CSR build (unchanged, tiny) ----------------

__global__ void k_setup(float* __restrict__ degf, int* __restrict__ degd, int N) {
    int n = blockIdx.x * blockDim.x + threadIdx.x;
    if (n < N) { degf[n] = 1.0f; degd[n] = 0; }
}

__global__ void k_deg2(const int* __restrict__ ei, float* __restrict__ degf,
                       int* __restrict__ degd, int E) {
    int e = blockIdx.x * blockDim.x + threadIdx.x;
    if (e < E) {
        unsafeAtomicAdd(&degf[ei[e]], 1.0f);   // out-degree (src)
        atomicAdd(&degd[ei[E + e]], 1);        // in-degree (dst)
    }
}

__global__ __launch_bounds__(1024) void k_scan(
        const int* __restrict__ degd, const float* __restrict__ degf,
        int* __restrict__ row_ptr, int* __restrict__ cursor,
        float* __restrict__ invdeg, int N, int E) {
    __shared__ int part[1024];
    int tid = threadIdx.x;
    int chunk = (N + 1023) / 1024;
    int lo = tid * chunk, hi = min(lo + chunk, N);
    int s = 0;
    for (int i = lo; i < hi; ++i) s += degd[i];
    part[tid] = s;
    __syncthreads();
    for (int off = 1; off < 1024; off <<= 1) {
        int v = (tid >= off) ? part[tid - off] : 0;
        __syncthreads();
        part[tid] += v;
        __syncthreads();
    }
    int base = (tid == 0) ? 0 : part[tid - 1];
    for (int i = lo; i < hi; ++i) {
        row_ptr[i] = base;
        cursor[i] = base;
        base += degd[i];
        invdeg[i] = 1.0f / degf[i];
    }
    if (tid == 1023) row_ptr[N] = E;
}

__global__ void k_scatter(const int* __restrict__ ei, int* __restrict__ cursor,
                          int* __restrict__ col, int E) {
    int e = blockIdx.x * blockDim.x + threadIdx.x;
    if (e < E) {
        int pos = atomicAdd(&cursor[ei[E + e]], 1);
        col[pos] = ei[e];
    }
}

// writes the comm_cost scalar via the proven normal-launch path
__global__ void k_tail(float* __restrict__ out, int last_idx, int E) {
    if (threadIdx.x == 0 && blockIdx.x == 0)
        out[last_idx] = (float)(3 * NUM_LAYERS * E);
}

// ---------------- fused: init + 10 layers, one cooperative dispatch ----------------
// 1 wave per node (grid-stride). LDS used only for intra-wave transposes
// (no barriers — same-wave LDS RAW is ordered by the compiler's lgkmcnt).

__global__ __launch_bounds__(256, 4) void k_fused(
        const float* __restrict__ A, const float* __restrict__ b,
        const float* __restrict__ x,
        const int* __restrict__ row_ptr, const int* __restrict__ col,
        const float* __restrict__ invdeg,
        __half* __restrict__ Ah,
        __half2* __restrict__ msg0, __half2* __restrict__ msg1,
        float* __restrict__ vw0, float* __restrict__ vw1,
        float* __restrict__ x0, float* __restrict__ xout,
        int N) {
    cg::grid_group gg = cg::this_grid();

    __shared__ float sdx[4][D];      // per-wave broadcast vector
    __shared__ float srow[4][D];     // per-wave matvec row results
    __shared__ float4 sg[4][2][16];  // per-wave gather transpose (u, y)

    int t = threadIdx.x, lane = t & 63, w = t >> 6;
    int wid = blockIdx.x * 4 + w;
    int nw = GRID * 4;
    int kq = lane >> 3;            // row-group within each k-round
    int cb = (lane & 7) * 8;       // col base for this lane
    int j = lane >> 4, q4 = lane & 15;

    // ---------- phase 0: init (A->fp16, y0 = 2Ax+b, emit msg0) ----------
    for (int n = wid; n < N; n += nw) {
        size_t off = (size_t)n * D + lane;
        float xv = x[off];
        sdx[w][lane] = xv;
        const float4* An = (const float4*)(A + (size_t)n * D * D);
        uint4* Ahn = (uint4*)(Ah + (size_t)n * D * D);
#pragma unroll
        for (int k = 0; k < 8; ++k) {
            int row = kq + 8 * k;
            int fidx = row * (D / 4) + (cb >> 2);
            float4 f0 = An[fidx];
            float4 f1 = An[fidx + 1];
            H8 pk;
            pk.h[0] = __float2half(f0.x);
            pk.h[1] = __float2half(f0.y);
            pk.h[2] = __float2half(f0.z);
            pk.h[3] = __float2half(f0.w);
            pk.h[4] = __float2half(f1.x);
            pk.h[5] = __float2half(f1.y);
            pk.h[6] = __float2half(f1.z);
            pk.h[7] = __float2half(f1.w);
            Ahn[lane + 64 * k] = pk.u;
            float p = f0.x * sdx[w][cb + 0] + f0.y * sdx[w][cb + 1]
                    + f0.z * sdx[w][cb + 2] + f0.w * sdx[w][cb + 3]
                    + f1.x * sdx[w][cb + 4] + f1.y * sdx[w][cb + 5]
                    + f1.z * sdx[w][cb + 6] + f1.w * sdx[w][cb + 7];
            p += __shfl_xor(p, 1);
            p += __shfl_xor(p, 2);
            p += __shfl_xor(p, 4);
            if ((lane & 7) == 0) srow[w][row] = p;
        }
        float yv = 2.0f * srow[w][lane] + b[off];
        float wd = invdeg[n];
        msg0[off] = __floats2half2_rn((xv - STEP * yv) * wd, yv * wd);
        x0[off] = xv;
        if (lane == 0) vw0[n] = wd;
    }
    __threadfence();
    gg.sync();

    // ---------- phases 1..10: layers ----------
    for (int l = 0; l < NUM_LAYERS; ++l) {
        const __half2* mc = (l & 1) ? msg1 : msg0;
        __half2* mn = (l & 1) ? msg0 : msg1;
        const float* vc = (l & 1) ? vw1 : vw0;
        float* vn = (l & 1) ? vw0 : vw1;
        float* xo = (l == NUM_LAYERS - 1) ? xout : nullptr;

        for (int n = wid; n < N; n += nw) {
            int rs = row_ptr[n], re = row_ptr[n + 1];

            // prefetch full 8KB A-tile into 32 VGPRs; hides under gather
            const uint4* Ap = (const uint4*)(Ah + (size_t)n * D * D);
            uint4 a[8];
#pragma unroll
            for (int k = 0; k < 8; ++k) a[k] = Ap[lane + 64 * k];

            size_t off = (size_t)n * D + lane;
            float2 msf = __half22float2(mc[off]);
            float x0v = x0[off];
            float vws = vc[n];
            float invd = invdeg[n];

            // gather: 8 edges per pass (2 per 16-lane group)
            float4 au = {0.f, 0.f, 0.f, 0.f}, ay = {0.f, 0.f, 0.f, 0.f};
            float av = 0.0f;
            for (int base = rs; base < re; base += 8) {
                int e0 = base + (j << 1), e1 = e0 + 1;
                bool b0 = e0 < re, b1 = e1 < re;
                int s0 = 0, s1 = 0;
                if (b0) s0 = col[e0];
                if (b1) s1 = col[e1];
                H8 m0, m1;
                m0.u = make_uint4(0u, 0u, 0u, 0u);
                m1.u = make_uint4(0u, 0u, 0u, 0u);
                float w0 = 0.f, w1 = 0.f;
                if (b0) m0.u = ((const uint4*)(mc + (size_t)s0 * D))[q4];
                if (b1) m1.u = ((const uint4*)(mc + (size_t)s1 * D))[q4];
                if (b0 && q4 == 0) w0 = vc[s0];
                if (b1 && q4 == 0) w1 = vc[s1];
                float2 f0 = __half22float2(m0.h2[0]);
                float2 f1 = __half22float2(m0.h2[1]);
                float2 f2 = __half22float2(m0.h2[2]);
                float2 f3 = __half22float2(m0.h2[3]);
                au.x += f0.x; ay.x += f0.y;
                au.y += f1.x; ay.y += f1.y;
                au.z += f2.x; ay.z += f2.y;
                au.w += f3.x; ay.w += f3.y;
                f0 = __half22float2(m1.h2[0]);
                f1 = __half22float2(m1.h2[1]);
                f2 = __half22float2(m1.h2[2]);
                f3 = __half22float2(m1.h2[3]);
                au.x += f0.x; ay.x += f0.y;
                au.y += f1.x; ay.y += f1.y;
                au.z += f2.x; ay.z += f2.y;
                au.w += f3.x; ay.w += f3.y;
                av += w0 + w1;
            }
            // combine the 4 edge groups
            au.x += __shfl_xor(au.x, 16); au.y += __shfl_xor(au.y, 16);
            au.z += __shfl_xor(au.z, 16); au.w += __shfl_xor(au.w, 16);
            au.x += __shfl_xor(au.x, 32); au.y += __shfl_xor(au.y, 32);
            au.z += __shfl_xor(au.z, 32); au.w += __shfl_xor(au.w, 32);
            ay.x += __shfl_xor(ay.x, 16); ay.y += __shfl_xor(ay.y, 16);
            ay.z += __shfl_xor(ay.z, 16); ay.w += __shfl_xor(ay.w, 16);
            ay.x += __shfl_xor(ay.x, 32); ay.y += __shfl_xor(ay.y, 32);
            ay.z += __shfl_xor(ay.z, 32); ay.w += __shfl_xor(ay.w, 32);
            av += __shfl_xor(av, 16);
            av += __shfl_xor(av, 32);
            av = __shfl(av, 0);

            // transpose float4-per-group -> scalar per lane via LDS (same wave)
            if (j == 0) { sg[w][0][q4] = au; sg[w][1][q4] = ay; }
            float ut = ((const float*)sg[w][0])[lane] + msf.x;
            float yt = ((const float*)sg[w][1])[lane] + msf.y;

            float vt = av + vws;
            float rvt = __builtin_amdgcn_rcpf(vt);
            float x1 = ut * rvt;
            float dx = x1 - x0v;
            x0[off] = x1;
            if (xo) xo[off] = x1;
            if (lane == 0) vn[n] = vt * invd;

            // matvec: yn = yt + 2*A@dx (LDS broadcast + LDS row scatter)
            sdx[w][lane] = dx;
#pragma unroll
            for (int k = 0; k < 8; ++k) {
                H8 aa; aa.u = a[k];
                float p = __half2float(aa.h[0]) * sdx[w][cb + 0]
                        + __half2float(aa.h[1]) * sdx[w][cb + 1]
                        + __half2float(aa.h[2]) * sdx[w][cb + 2]
                        + __half2float(aa.h[3]) * sdx[w][cb + 3]
                        + __half2float(aa.h[4]) * sdx[w][cb + 4]
                        + __half2float(aa.h[5]) * sdx[w][cb + 5]
                        + __half2float(aa.h[6]) * sdx[w][cb + 6]
                        + __half2float(aa.h[7]) * sdx[w][cb + 7];
                p += __shfl_xor(p, 1);
                p += __shfl_xor(p, 2);
                p += __shfl_xor(p, 4);
                if ((lane & 7) == 0) srow[w][kq + 8 * k] = p;
            }
            float yn = yt + 2.0f * srow[w][lane];
            mn[off] = __floats2half2_rn((ut - STEP * yn) * invd, yn * invd);
        }
        if (l != NUM_LAYERS - 1) {
            __threadfence();
            gg.sync();
        }
    }
}

// ---------------- host launcher ----------------

extern "C" void kernel_launch(void* const* d_in, const int* in_sizes, int n_in,
                              void* d_out, int out_size, void* d_ws, size_t ws_size,
                              hipStream_t stream) {
    const float* A  = (const float*)d_in[0];
    const float* b  = (const float*)d_in[1];
    const float* x  = (const float*)d_in[2];
    const int*   ei = (const int*)d_in[3];

    const int N = in_sizes[1] / D;        // b is [N, D]
    const int E = in_sizes[3] / 2;        // edge_index is [2, E]
    const size_t ND = (size_t)N * D;

    char* ws = (char*)d_ws;
    __half* Ah = (__half*)ws;                               // N*D*D halves
    __half2* msg0 = (__half2*)(ws + ND * D * sizeof(__half));
    __half2* msg1 = msg0 + ND;
    float* x0   = (float*)(msg1 + ND);
    float* vw0  = x0 + ND;
    float* vw1  = vw0 + N;
    float* invdeg = vw1 + N;
    float* degf = invdeg + N;
    int* degd    = (int*)(degf + N);
    int* row_ptr = degd + N;
    int* cursor  = row_ptr + N + 4;
    int* col     = cursor + N;

    k_setup<<<(N + 255) / 256, 256, 0, stream>>>(degf, degd, N);
    k_deg2<<<(E + 255) / 256, 256, 0, stream>>>(ei, degf, degd, E);
    k_scan<<<1, 1024, 0, stream>>>(degd, degf, row_ptr, cursor, invdeg, N, E);
    k_scatter<<<(E + 255) / 256, 256, 0, stream>>>(ei, cursor, col, E);

    float* xout = (float*)d_out;
    int Nv = N;

    void* args[] = {
        (void*)&A, (void*)&b, (void*)&x,
        (void*)&row_ptr, (void*)&col, (void*)&invdeg,
        (void*)&Ah, (void*)&msg0, (void*)&msg1,
        (void*)&vw0, (void*)&vw1, (void*)&x0, (void*)&xout,
        (void*)&Nv
    };
    hipLaunchCooperativeKernel((void*)k_fused, dim3(GRID), dim3(256),
                               args, 0, stream);

    k_tail<<<1, 64, 0, stream>>>(xout, out_size - 1, E);
}

// Round 5
// 1028.217 us; speedup vs baseline: 3.2047x; 3.2047x over previous
//
#include <hip/hip_runtime.h>
#include <hip/hip_bf16.h>
#include <hip/hip_fp16.h>

#define STEP 0.01f
#define D 64
#define NUM_LAYERS 10

union H4 { uint2 u; __half h[4]; };
union H8 { uint4 u; __half2 h2[4]; __half h[8]; };

// ---------------- CSR build ----------------

__global__ void k_setup(float* __restrict__ degf, int* __restrict__ degd, int N) {
    int n = blockIdx.x * blockDim.x + threadIdx.x;
    if (n < N) { degf[n] = 1.0f; degd[n] = 0; }
}

__global__ void k_deg2(const int* __restrict__ ei, float* __restrict__ degf,
                       int* __restrict__ degd, int E) {
    int e = blockIdx.x * blockDim.x + threadIdx.x;
    if (e < E) {
        unsafeAtomicAdd(&degf[ei[e]], 1.0f);   // out-degree (src)
        atomicAdd(&degd[ei[E + e]], 1);        // in-degree (dst)
    }
}

__global__ __launch_bounds__(1024) void k_scan(
        const int* __restrict__ degd, const float* __restrict__ degf,
        int* __restrict__ row_ptr, int* __restrict__ cursor,
        float* __restrict__ invdeg, int N, int E) {
    __shared__ int part[1024];
    int tid = threadIdx.x;
    int chunk = (N + 1023) / 1024;
    int lo = tid * chunk, hi = min(lo + chunk, N);
    int s = 0;
    for (int i = lo; i < hi; ++i) s += degd[i];
    part[tid] = s;
    __syncthreads();
    for (int off = 1; off < 1024; off <<= 1) {
        int v = (tid >= off) ? part[tid - off] : 0;
        __syncthreads();
        part[tid] += v;
        __syncthreads();
    }
    int base = (tid == 0) ? 0 : part[tid - 1];
    for (int i = lo; i < hi; ++i) {
        row_ptr[i] = base;
        cursor[i] = base;
        base += degd[i];
        invdeg[i] = 1.0f / degf[i];
    }
    if (tid == 1023) row_ptr[N] = E;
}

__global__ void k_scatter(const int* __restrict__ ei, int* __restrict__ cursor,
                          int* __restrict__ col, int E) {
    int e = blockIdx.x * blockDim.x + threadIdx.x;
    if (e < E) {
        int pos = atomicAdd(&cursor[ei[E + e]], 1);
        col[pos] = ei[e];
    }
}

// writes the comm_cost scalar (proven normal-launch path)
__global__ void k_tail(float* __restrict__ out, int last_idx, int E) {
    if (threadIdx.x == 0 && blockIdx.x == 0)
        out[last_idx] = (float)(3 * NUM_LAYERS * E);
}

// ---------------- init: A->fp16 + y=2Ax+b + emit pre-weighted fp16 msgs ----------------

__global__ __launch_bounds__(256) void k_init(
        const float* __restrict__ A, const float* __restrict__ b,
        const float* __restrict__ x, const float* __restrict__ invdeg,
        __half* __restrict__ Ah, __half2* __restrict__ msg,
        float* __restrict__ vw, float* __restrict__ x0, int N) {
    __shared__ __align__(16) float sx[D];
    __shared__ float syv[D];
    int n = blockIdx.x, t = threadIdx.x;
    int lane = t & 63, w = t >> 6, colgrp = lane & 15;
    if (t < D) sx[t] = x[(size_t)n * D + t];
    __syncthreads();
    const float* An = A + (size_t)n * D * D;
    __half* Ahn = Ah + (size_t)n * D * D;
    float4 xr = ((const float4*)sx)[colgrp];
    int rbase = w * 16 + (lane >> 4);
#pragma unroll
    for (int g = 0; g < 4; ++g) {
        int row = rbase + g * 4;
        float4 a = ((const float4*)(An + (size_t)row * D))[colgrp];
        H4 pk;
        pk.h[0] = __float2half(a.x);
        pk.h[1] = __float2half(a.y);
        pk.h[2] = __float2half(a.z);
        pk.h[3] = __float2half(a.w);
        ((uint2*)(Ahn + (size_t)row * D))[colgrp] = pk.u;
        float p = a.x * xr.x + a.y * xr.y + a.z * xr.z + a.w * xr.w;
        p += __shfl_xor(p, 1);
        p += __shfl_xor(p, 2);
        p += __shfl_xor(p, 4);
        p += __shfl_xor(p, 8);
        if (colgrp == 0) syv[row] = 2.0f * p + b[(size_t)n * D + row];
    }
    __syncthreads();
    if (t < D) {
        float wd = invdeg[n];
        float xv = sx[t];
        float yv = syv[t];
        msg[(size_t)n * D + t] = __floats2half2_rn((xv - STEP * yv) * wd, yv * wd);
        x0[(size_t)n * D + t] = xv;
        if (t == 0) vw[n] = wd;
    }
}

// ---------------- layer part 1: gather only (no Ah — low VGPR, max occupancy) ----------------

__global__ __launch_bounds__(256) void k_gather(
        const int* __restrict__ row_ptr, const int* __restrict__ col,
        const __half2* __restrict__ msg, const float* __restrict__ vw,
        const float* __restrict__ invdeg,
        float* __restrict__ vwn, float* __restrict__ x0, float* __restrict__ xout,
        float* __restrict__ dxb, float* __restrict__ utb, float* __restrict__ ytb,
        int N) {
    int t = threadIdx.x;
    int lane = t & 63, w = t >> 6;
    int n = blockIdx.x * 4 + w;      // one wave per node
    if (n >= N) return;

    int j = lane >> 4, q4 = lane & 15;
    int rs = row_ptr[n], re = row_ptr[n + 1];

    // gather: 8 edges per pass (2 per 16-lane group); col loads precede msg loads
    float4 au = {0.f, 0.f, 0.f, 0.f}, ay = {0.f, 0.f, 0.f, 0.f};
    float av = 0.0f;
    for (int base = rs; base < re; base += 8) {
        int e0 = base + (j << 1), e1 = e0 + 1;
        bool b0 = e0 < re, b1 = e1 < re;
        int s0 = 0, s1 = 0;
        if (b0) s0 = col[e0];
        if (b1) s1 = col[e1];
        H8 m0, m1;
        m0.u = make_uint4(0u, 0u, 0u, 0u);
        m1.u = make_uint4(0u, 0u, 0u, 0u);
        float w0 = 0.f, w1 = 0.f;
        if (b0) m0.u = ((const uint4*)(msg + (size_t)s0 * D))[q4];
        if (b1) m1.u = ((const uint4*)(msg + (size_t)s1 * D))[q4];
        if (b0 && q4 == 0) w0 = vw[s0];
        if (b1 && q4 == 0) w1 = vw[s1];
        float2 f0 = __half22float2(m0.h2[0]);
        float2 f1 = __half22float2(m0.h2[1]);
        float2 f2 = __half22float2(m0.h2[2]);
        float2 f3 = __half22float2(m0.h2[3]);
        au.x += f0.x; ay.x += f0.y;
        au.y += f1.x; ay.y += f1.y;
        au.z += f2.x; ay.z += f2.y;
        au.w += f3.x; ay.w += f3.y;
        f0 = __half22float2(m1.h2[0]);
        f1 = __half22float2(m1.h2[1]);
        f2 = __half22float2(m1.h2[2]);
        f3 = __half22float2(m1.h2[3]);
        au.x += f0.x; ay.x += f0.y;
        au.y += f1.x; ay.y += f1.y;
        au.z += f2.x; ay.z += f2.y;
        au.w += f3.x; ay.w += f3.y;
        av += w0 + w1;
    }

    // self terms issued here; their latency hides under the shuffle reduce below
    size_t off = (size_t)n * D + lane;
    float2 msf = __half22float2(msg[off]);
    float x0v = x0[off];
    float vws = vw[n];
    float invd = invdeg[n];

    // sum the 4 edge groups (lanes xor 16, 32)
    au.x += __shfl_xor(au.x, 16); au.y += __shfl_xor(au.y, 16);
    au.z += __shfl_xor(au.z, 16); au.w += __shfl_xor(au.w, 16);
    au.x += __shfl_xor(au.x, 32); au.y += __shfl_xor(au.y, 32);
    au.z += __shfl_xor(au.z, 32); au.w += __shfl_xor(au.w, 32);
    ay.x += __shfl_xor(ay.x, 16); ay.y += __shfl_xor(ay.y, 16);
    ay.z += __shfl_xor(ay.z, 16); ay.w += __shfl_xor(ay.w, 16);
    ay.x += __shfl_xor(ay.x, 32); ay.y += __shfl_xor(ay.y, 32);
    ay.z += __shfl_xor(ay.z, 32); ay.w += __shfl_xor(ay.w, 32);
    av += __shfl_xor(av, 16);
    av += __shfl_xor(av, 32);
    av = __shfl(av, 0);

    // transpose float4-per-group -> scalar per lane (lane d owns dim d)
    int src = lane >> 2, c = lane & 3;
    float ua = __shfl(au.x, src), ub = __shfl(au.y, src),
          uc = __shfl(au.z, src), ud = __shfl(au.w, src);
    float ya = __shfl(ay.x, src), yb = __shfl(ay.y, src),
          yc = __shfl(ay.z, src), yd = __shfl(ay.w, src);
    float ut = (c & 2) ? ((c & 1) ? ud : uc) : ((c & 1) ? ub : ua);
    float yt = (c & 2) ? ((c & 1) ? yd : yc) : ((c & 1) ? yb : ya);
    ut += msf.x;
    yt += msf.y;

    float vt = av + vws;
    float rvt = __builtin_amdgcn_rcpf(vt);
    float x1 = ut * rvt;
    float dx = x1 - x0v;
    x0[off] = x1;
    if (xout) xout[off] = x1;
    if (lane == 0) vwn[n] = vt * invd;

    dxb[off] = dx;
    utb[off] = ut;
    ytb[off] = yt;
}

// ---------------- layer part 2: pure Ah stream + matvec + emit ----------------
// All loads independent, issued back-to-back: clean streaming at HBM/L3 BW.

__global__ __launch_bounds__(256) void k_matvec(
        const __half* __restrict__ Ah,
        const float* __restrict__ dxb, const float* __restrict__ utb,
        const float* __restrict__ ytb, const float* __restrict__ invdeg,
        __half2* __restrict__ msgn, int N) {
    int t = threadIdx.x;
    int lane = t & 63, w = t >> 6;
    int n = blockIdx.x * 4 + w;      // one wave per node
    if (n >= N) return;

    size_t off = (size_t)n * D + lane;
    int cb = (lane & 7) * 8;

    // small parameter loads (issued first; drained together with the A stream)
    float ut = utb[off];
    float yt = ytb[off];
    float invd = invdeg[n];
    const float4* dxp = (const float4*)(dxb + (size_t)n * D);
    float4 d0 = dxp[cb >> 2];        // dx[cb..cb+3]  (8-lane broadcast)
    float4 d1 = dxp[(cb >> 2) + 1];  // dx[cb+4..cb+7]

    // the 8KB A-tile: 8 independent fully-coalesced 1KB wave loads
    const uint4* Ap = (const uint4*)(Ah + (size_t)n * D * D);
    uint4 a[8];
#pragma unroll
    for (int k = 0; k < 8; ++k) a[k] = Ap[lane + 64 * k];

    float dxv[8] = {d0.x, d0.y, d0.z, d0.w, d1.x, d1.y, d1.z, d1.w};

    // lane l: rows (l>>3)+8k, cols cb..cb+7
    float pk[8];
#pragma unroll
    for (int k = 0; k < 8; ++k) {
        H8 aa; aa.u = a[k];
        float p = 0.f;
#pragma unroll
        for (int jj = 0; jj < 8; ++jj)
            p += __half2float(aa.h[jj]) * dxv[jj];
        p += __shfl_xor(p, 1);
        p += __shfl_xor(p, 2);
        p += __shfl_xor(p, 4);
        pk[k] = p;                    // all 8 lanes of row-group hold row (l>>3)+8k
    }
    // lane d wants row d = (d&7) + 8*(d>>3): pull pk[k] from lane (d&7)*8, pick k=d>>3
    int srcg = (lane & 7) * 8;
    float pr[8];
#pragma unroll
    for (int k = 0; k < 8; ++k) pr[k] = __shfl(pk[k], srcg);
    int kk = lane >> 3;
    float prow = (kk & 4) ? ((kk & 2) ? ((kk & 1) ? pr[7] : pr[6])
                                      : ((kk & 1) ? pr[5] : pr[4]))
                          : ((kk & 2) ? ((kk & 1) ? pr[3] : pr[2])
                                      : ((kk & 1) ? pr[1] : pr[0]));
    float yn = yt + 2.0f * prow;
    msgn[off] = __floats2half2_rn((ut - STEP * yn) * invd, yn * invd);
}

// ---------------- host launcher ----------------

extern "C" void kernel_launch(void* const* d_in, const int* in_sizes, int n_in,
                              void* d_out, int out_size, void* d_ws, size_t ws_size,
                              hipStream_t stream) {
    const float* A  = (const float*)d_in[0];
    const float* b  = (const float*)d_in[1];
    const float* x  = (const float*)d_in[2];
    const int*   ei = (const int*)d_in[3];

    const int N = in_sizes[1] / D;        // b is [N, D]
    const int E = in_sizes[3] / 2;        // edge_index is [2, E]
    const size_t ND = (size_t)N * D;

    char* ws = (char*)d_ws;
    __half* Ah = (__half*)ws;                               // N*D*D halves
    __half2* msg0 = (__half2*)(ws + ND * D * sizeof(__half));
    __half2* msg1 = msg0 + ND;
    float* x0   = (float*)(msg1 + ND);
    float* vw0  = x0 + ND;
    float* vw1  = vw0 + N;
    float* invdeg = vw1 + N;
    float* degf = invdeg + N;
    int* degd    = (int*)(degf + N);
    int* row_ptr = degd + N;
    int* cursor  = row_ptr + N + 4;
    int* col     = cursor + N;
    float* dxb  = (float*)(col + E);
    float* utb  = dxb + ND;
    float* ytb  = utb + ND;

    k_setup<<<(N + 255) / 256, 256, 0, stream>>>(degf, degd, N);
    k_deg2<<<(E + 255) / 256, 256, 0, stream>>>(ei, degf, degd, E);
    k_scan<<<1, 1024, 0, stream>>>(degd, degf, row_ptr, cursor, invdeg, N, E);
    k_scatter<<<(E + 255) / 256, 256, 0, stream>>>(ei, cursor, col, E);
    k_init<<<N, 256, 0, stream>>>(A, b, x, invdeg, Ah, msg0, vw0, x0, N);

    __half2 *mc = msg0, *mn = msg1;
    float *vc = vw0, *vn = vw1;
    int nb = (N + 3) / 4;
    for (int l = 0; l < NUM_LAYERS; ++l) {
        float* xout = (l == NUM_LAYERS - 1) ? (float*)d_out : nullptr;
        k_gather<<<nb, 256, 0, stream>>>(row_ptr, col, mc, vc, invdeg,
                                         vn, x0, xout, dxb, utb, ytb, N);
        k_matvec<<<nb, 256, 0, stream>>>(Ah, dxb, utb, ytb, invdeg, mn, N);
        __half2* tm = mc; mc = mn; mn = tm;
        float* tv = vc; vc = vn; vn = tv;
    }

    k_tail<<<1, 64, 0, stream>>>((float*)d_out, out_size - 1, E);
}

// Round 7
// 928.599 us; speedup vs baseline: 3.5485x; 1.1073x over previous
//
#include <hip/hip_runtime.h>
#include <hip/hip_bf16.h>
#include <hip/hip_fp16.h>

#define STEP 0.01f
#define D 64
#define NUM_LAYERS 10

union H4 { uint2 u; __half h[4]; };
union H8 { uint4 u; __half2 h2[4]; __half h[8]; };

typedef float f32x2 __attribute__((ext_vector_type(2)));

// ---------------- CSR build ----------------

__global__ void k_setup(float* __restrict__ degf, int* __restrict__ degd, int N) {
    int n = blockIdx.x * blockDim.x + threadIdx.x;
    if (n < N) { degf[n] = 1.0f; degd[n] = 0; }
}

__global__ void k_deg2(const int* __restrict__ ei, float* __restrict__ degf,
                       int* __restrict__ degd, int E) {
    int e = blockIdx.x * blockDim.x + threadIdx.x;
    if (e < E) {
        unsafeAtomicAdd(&degf[ei[e]], 1.0f);   // out-degree (src)
        atomicAdd(&degd[ei[E + e]], 1);        // in-degree (dst)
    }
}

__global__ __launch_bounds__(1024) void k_scan(
        const int* __restrict__ degd, const float* __restrict__ degf,
        int* __restrict__ row_ptr, int* __restrict__ cursor,
        float* __restrict__ invdeg, int N, int E) {
    __shared__ int part[1024];
    int tid = threadIdx.x;
    int chunk = (N + 1023) / 1024;
    int lo = tid * chunk, hi = min(lo + chunk, N);
    int s = 0;
    for (int i = lo; i < hi; ++i) s += degd[i];
    part[tid] = s;
    __syncthreads();
    for (int off = 1; off < 1024; off <<= 1) {
        int v = (tid >= off) ? part[tid - off] : 0;
        __syncthreads();
        part[tid] += v;
        __syncthreads();
    }
    int base = (tid == 0) ? 0 : part[tid - 1];
    for (int i = lo; i < hi; ++i) {
        row_ptr[i] = base;
        cursor[i] = base;
        base += degd[i];
        invdeg[i] = 1.0f / degf[i];
    }
    if (tid == 1023) row_ptr[N] = E;
}

__global__ void k_scatter(const int* __restrict__ ei, int* __restrict__ cursor,
                          int* __restrict__ col, int E) {
    int e = blockIdx.x * blockDim.x + threadIdx.x;
    if (e < E) {
        int pos = atomicAdd(&cursor[ei[E + e]], 1);
        col[pos] = ei[e];
    }
}

// ---------------- init: A->fp8 + y=2Ax+b (fp32 exact) + emit pre-weighted fp16 msgs ----------------

__global__ __launch_bounds__(256) void k_init(
        const float* __restrict__ A, const float* __restrict__ b,
        const float* __restrict__ x, const float* __restrict__ invdeg,
        unsigned char* __restrict__ Ah8, __half2* __restrict__ msg,
        float* __restrict__ vw, float* __restrict__ x0, int N) {
    __shared__ __align__(16) float sx[D];
    __shared__ float syv[D];
    int n = blockIdx.x, t = threadIdx.x;
    int lane = t & 63, w = t >> 6, colgrp = lane & 15;
    if (t < D) sx[t] = x[(size_t)n * D + t];
    __syncthreads();
    const float* An = A + (size_t)n * D * D;
    unsigned char* A8n = Ah8 + (size_t)n * D * D;   // 1 byte/elem, row stride D
    float4 xr = ((const float4*)sx)[colgrp];
    int rbase = w * 16 + (lane >> 4);
#pragma unroll
    for (int g = 0; g < 4; ++g) {
        int row = rbase + g * 4;
        float4 a = ((const float4*)(An + (size_t)row * D))[colgrp];
        // pack 4 floats -> 4 fp8 bytes (RNE, e4m3)
        int d8 = __builtin_amdgcn_cvt_pk_fp8_f32(a.x, a.y, 0, false);
        d8 = __builtin_amdgcn_cvt_pk_fp8_f32(a.z, a.w, d8, true);
        ((unsigned int*)(A8n + (size_t)row * D))[colgrp] = (unsigned int)d8;
        float p = a.x * xr.x + a.y * xr.y + a.z * xr.z + a.w * xr.w;
        p += __shfl_xor(p, 1);
        p += __shfl_xor(p, 2);
        p += __shfl_xor(p, 4);
        p += __shfl_xor(p, 8);
        if (colgrp == 0) syv[row] = 2.0f * p + b[(size_t)n * D + row];
    }
    __syncthreads();
    if (t < D) {
        float wd = invdeg[n];
        float xv = sx[t];
        float yv = syv[t];
        msg[(size_t)n * D + t] = __floats2half2_rn((xv - STEP * yv) * wd, yv * wd);
        x0[(size_t)n * D + t] = xv;
        if (t == 0) vw[n] = wd;
    }
}

// ---------------- fused layer (R0 structure; phase 3 reads fp8 A) ----------------

__global__ __launch_bounds__(256) void k_layer(
        const unsigned char* __restrict__ Ah8,
        const int* __restrict__ row_ptr, const int* __restrict__ col,
        const __half2* __restrict__ msg, const float* __restrict__ vw,
        const float* __restrict__ invdeg,
        __half2* __restrict__ msgn, float* __restrict__ vwn,
        float* __restrict__ x0, float* __restrict__ xout,
        int last_idx, float comm, int N) {
    __shared__ float su[4][D];
    __shared__ float sy[4][D];
    __shared__ float sv[4];
    __shared__ __align__(16) float sdx[D];
    __shared__ float sun[D];
    __shared__ float sytot[D];
    __shared__ float syn[D];
    __shared__ float svn;

    int n = blockIdx.x, t = threadIdx.x;
    int lane = t & 63, w = t >> 6;
    int j = lane >> 4, q4 = lane & 15;

    // phase 1: gather — 4 edges per wave-pass, one uint4 (4x half2 (u,y)) per lane
    int rs = row_ptr[n], re = row_ptr[n + 1];
    float4 au = {0.f, 0.f, 0.f, 0.f}, ay = {0.f, 0.f, 0.f, 0.f};
    float av = 0.0f;
    for (int base = rs + w * 4; base < re; base += 16) {
        int e = base + j;
        if (e < re) {
            int s = col[e];
            H8 m;
            m.u = ((const uint4*)(msg + (size_t)s * D))[q4];
            float2 f0 = __half22float2(m.h2[0]);
            float2 f1 = __half22float2(m.h2[1]);
            float2 f2 = __half22float2(m.h2[2]);
            float2 f3 = __half22float2(m.h2[3]);
            au.x += f0.x; ay.x += f0.y;
            au.y += f1.x; ay.y += f1.y;
            au.z += f2.x; ay.z += f2.y;
            au.w += f3.x; ay.w += f3.y;
            if (q4 == 0) av += vw[s];
        }
    }
    // reduce across the 4 edge slots (lanes xor 16, 32)
    au.x += __shfl_xor(au.x, 16); au.y += __shfl_xor(au.y, 16);
    au.z += __shfl_xor(au.z, 16); au.w += __shfl_xor(au.w, 16);
    au.x += __shfl_xor(au.x, 32); au.y += __shfl_xor(au.y, 32);
    au.z += __shfl_xor(au.z, 32); au.w += __shfl_xor(au.w, 32);
    ay.x += __shfl_xor(ay.x, 16); ay.y += __shfl_xor(ay.y, 16);
    ay.z += __shfl_xor(ay.z, 16); ay.w += __shfl_xor(ay.w, 16);
    ay.x += __shfl_xor(ay.x, 32); ay.y += __shfl_xor(ay.y, 32);
    ay.z += __shfl_xor(ay.z, 32); ay.w += __shfl_xor(ay.w, 32);
    av += __shfl_xor(av, 16);
    av += __shfl_xor(av, 32);
    if (j == 0) {
        ((float4*)su[w])[q4] = au;
        ((float4*)sy[w])[q4] = ay;
        if (q4 == 0) sv[w] = av;
    }
    __syncthreads();

    // phase 2: combine + self term; x1 = un/vn; dx = x1 - x0
    if (w == 0) {
        size_t off = (size_t)n * D + lane;
        float2 self = __half22float2(msg[off]);
        float ut = su[0][lane] + su[1][lane] + su[2][lane] + su[3][lane] + self.x;
        float yt = sy[0][lane] + sy[1][lane] + sy[2][lane] + sy[3][lane] + self.y;
        float vt = sv[0] + sv[1] + sv[2] + sv[3] + vw[n];
        float x1 = ut / vt;
        sdx[lane] = x1 - x0[off];
        x0[off] = x1;
        if (xout) xout[off] = x1;
        sun[lane] = ut;
        sytot[lane] = yt;
        if (lane == 0) svn = vt;
    }
    __syncthreads();

    // phase 3: yn = yt + 2*A@dx  (fp8 A, 4KB/block fully-coalesced loads)
    {
        const uint2* Ahp = (const uint2*)(Ah8 + (size_t)n * D * D);
        int cb = (t & 7) * 8;
        int r0 = t >> 3;
        uint2 a0 = Ahp[t];          // row r0,    cols cb..cb+7 (8 fp8 bytes)
        uint2 a1 = Ahp[256 + t];    // row 32+r0, cols cb..cb+7
        float p0 = 0.0f, p1 = 0.0f;
        f32x2 q;
        q = __builtin_amdgcn_cvt_pk_f32_fp8((int)a0.x, false);
        p0 += q.x * sdx[cb + 0] + q.y * sdx[cb + 1];
        q = __builtin_amdgcn_cvt_pk_f32_fp8((int)a0.x, true);
        p0 += q.x * sdx[cb + 2] + q.y * sdx[cb + 3];
        q = __builtin_amdgcn_cvt_pk_f32_fp8((int)a0.y, false);
        p0 += q.x * sdx[cb + 4] + q.y * sdx[cb + 5];
        q = __builtin_amdgcn_cvt_pk_f32_fp8((int)a0.y, true);
        p0 += q.x * sdx[cb + 6] + q.y * sdx[cb + 7];
        q = __builtin_amdgcn_cvt_pk_f32_fp8((int)a1.x, false);
        p1 += q.x * sdx[cb + 0] + q.y * sdx[cb + 1];
        q = __builtin_amdgcn_cvt_pk_f32_fp8((int)a1.x, true);
        p1 += q.x * sdx[cb + 2] + q.y * sdx[cb + 3];
        q = __builtin_amdgcn_cvt_pk_f32_fp8((int)a1.y, false);
        p1 += q.x * sdx[cb + 4] + q.y * sdx[cb + 5];
        q = __builtin_amdgcn_cvt_pk_f32_fp8((int)a1.y, true);
        p1 += q.x * sdx[cb + 6] + q.y * sdx[cb + 7];
        p0 += __shfl_xor(p0, 1); p1 += __shfl_xor(p1, 1);
        p0 += __shfl_xor(p0, 2); p1 += __shfl_xor(p1, 2);
        p0 += __shfl_xor(p0, 4); p1 += __shfl_xor(p1, 4);
        if ((lane & 7) == 0) {
            syn[r0]      = sytot[r0]      + 2.0f * p0;
            syn[32 + r0] = sytot[32 + r0] + 2.0f * p1;
        }
    }
    __syncthreads();

    // phase 4: emit next layer's pre-weighted fp16 messages
    if (t < D) {
        float wd = invdeg[n];
        float ynf = syn[t];
        msgn[(size_t)n * D + t] = __floats2half2_rn((sun[t] - STEP * ynf) * wd, ynf * wd);
        if (t == 0) vwn[n] = svn * wd;
    }
    if (xout && n == 0 && t == 0) xout[last_idx] = comm;
}

// ---------------- host launcher ----------------

extern "C" void kernel_launch(void* const* d_in, const int* in_sizes, int n_in,
                              void* d_out, int out_size, void* d_ws, size_t ws_size,
                              hipStream_t stream) {
    const float* A  = (const float*)d_in[0];
    const float* b  = (const float*)d_in[1];
    const float* x  = (const float*)d_in[2];
    const int*   ei = (const int*)d_in[3];

    const int N = in_sizes[1] / D;        // b is [N, D]
    const int E = in_sizes[3] / 2;        // edge_index is [2, E]
    const size_t ND = (size_t)N * D;

    char* ws = (char*)d_ws;
    unsigned char* Ah8 = (unsigned char*)ws;                // N*D*D bytes (fp8)
    __half2* msg0 = (__half2*)(ws + ND * D);
    __half2* msg1 = msg0 + ND;
    float* x0   = (float*)(msg1 + ND);
    float* vw0  = x0 + ND;
    float* vw1  = vw0 + N;
    float* invdeg = vw1 + N;
    float* degf = invdeg + N;
    int* degd    = (int*)(degf + N);
    int* row_ptr = degd + N;
    int* cursor  = row_ptr + N + 4;
    int* col     = cursor + N;

    k_setup<<<(N + 255) / 256, 256, 0, stream>>>(degf, degd, N);
    k_deg2<<<(E + 255) / 256, 256, 0, stream>>>(ei, degf, degd, E);
    k_scan<<<1, 1024, 0, stream>>>(degd, degf, row_ptr, cursor, invdeg, N, E);
    k_scatter<<<(E + 255) / 256, 256, 0, stream>>>(ei, cursor, col, E);
    k_init<<<N, 256, 0, stream>>>(A, b, x, invdeg, Ah8, msg0, vw0, x0, N);

    float comm = (float)(3 * NUM_LAYERS * E);
    __half2 *mc = msg0, *mn = msg1;
    float *vc = vw0, *vn = vw1;
    for (int l = 0; l < NUM_LAYERS; ++l) {
        float* xout = (l == NUM_LAYERS - 1) ? (float*)d_out : nullptr;
        k_layer<<<N, 256, 0, stream>>>(Ah8, row_ptr, col, mc, vc, invdeg,
                                       mn, vn, x0, xout, out_size - 1, comm, N);
        __half2* tm = mc; mc = mn; mn = tm;
        float* tv = vc; vc = vn; vn = tv;
    }
}